// Round 1
// baseline (69.594 us; speedup 1.0000x reference)
//
#include <hip/hip_runtime.h>

#define NB   8192
#define NJ   14
#define NC   18
#define COLS 14
#define PIX  196          // 14*14
#define CHE  (NC * PIX)   // 3528

__global__ __launch_bounds__(256) void mse_partial_kernel(
    const float* __restrict__ h, const float* __restrict__ t,
    const int* __restrict__ v, float* __restrict__ partials,
    float* __restrict__ vsums)
{
    __shared__ float wl[9];           // gaussian taps (unnormalized)
    __shared__ float g[COLS][COLS];   // g[p][r]: blurred delta at p, sampled at r
    __shared__ float filt[CHE];       // 14.1 KB
    __shared__ float str[NJ * 2];
    __shared__ int   svr[NJ * 2];
    __shared__ int   sxi[NJ], syi[NJ], svis[NJ];
    __shared__ int   ch_np[NC], ch_mask[NC];
    __shared__ int   ch_py[NC][3], ch_px[NC][3];
    __shared__ float ch_mn[NC], ch_inv[NC];
    __shared__ int   svsum;
    __shared__ float wred[4];

    const int b   = blockIdx.x;
    const int tid = threadIdx.x;

    // phase 0: raw loads + gaussian taps
    if (tid < 9) { float x = (float)(tid - 4); wl[tid] = expf(-0.5f * x * x); }
    if (tid < 28) { str[tid] = t[b * 28 + tid]; svr[tid] = v[b * 28 + tid]; }
    __syncthreads();

    // phase 1: joint indices/visibility, g table, v-sum
    if (tid < NJ) {
        float fx = str[tid * 2 + 0] * 14.0f;
        float fy = str[tid * 2 + 1] * 14.0f;
        int xi = (int)fx; xi = xi < 0 ? 0 : (xi > 13 ? 13 : xi);
        int yi = (int)fy; yi = yi < 0 ? 0 : (yi > 13 ? 13 : yi);
        sxi[tid] = xi; syi[tid] = yi; svis[tid] = (svr[tid * 2] == 1);
    }
    if (tid < PIX) {
        float wsum = 0.f;
        #pragma unroll
        for (int k = 0; k < 9; k++) wsum += wl[k];
        int p = tid / 14, r = tid % 14;
        float acc = 0.f;
        #pragma unroll
        for (int k = 0; k < 9; k++) {
            int m  = r + k - 4;                              // index into unpadded signal
            int sm = m < 0 ? (-m - 1) : (m > 13 ? 27 - m : m); // symmetric reflect
            if (sm == p) acc += wl[k];
        }
        g[p][r] = acc / wsum;
    }
    if (tid == 0) { int s = 0; for (int i = 0; i < 28; i++) s += svr[i]; svsum = s; }
    __syncthreads();

    // phase 2: per-channel metadata (positions, mask)
    if (tid < NJ) {
        ch_np[tid]   = svis[tid] ? 1 : 0;
        ch_mask[tid] = svis[tid];
        ch_py[tid][0] = syi[tid]; ch_px[tid][0] = sxi[tid];
    } else if (tid < NC) {
        int gi = tid - NJ;
        int np = 0, any = 0;
        int py[3], px[3];
        for (int jj = 0; jj < 3; jj++) {
            int j = gi * 3 + jj;
            if (svis[j]) {
                any = 1;
                bool dup = false;
                for (int q = 0; q < np; q++)
                    if (py[q] == syi[j] && px[q] == sxi[j]) dup = true;
                if (!dup) { py[np] = syi[j]; px[np] = sxi[j]; np++; }
            }
        }
        ch_np[tid] = np; ch_mask[tid] = any;
        for (int q = 0; q < np; q++) { ch_py[tid][q] = py[q]; ch_px[tid][q] = px[q]; }
    }
    __syncthreads();

    // phase 3: materialize filt (sum of separable outer products)
    for (int i = tid; i < CHE; i += 256) {
        int c   = i / PIX;
        int pix = i - c * PIX;
        int r   = pix / 14;
        int cc  = pix - r * 14;
        float f = 0.f;
        int np = ch_np[c];
        for (int q = 0; q < np; q++) f += g[ch_py[c][q]][r] * g[ch_px[c][q]][cc];
        filt[i] = f;
    }
    __syncthreads();

    // phase 4: per-channel min/max (8 lanes per channel, shuffle reduce)
    if (tid < 144) {
        int c = tid >> 3, l8 = tid & 7;
        float mn = 1e30f, mx = -1e30f;
        for (int pix = l8; pix < PIX; pix += 8) {
            float f = filt[c * PIX + pix];
            mn = fminf(mn, f); mx = fmaxf(mx, f);
        }
        #pragma unroll
        for (int m = 1; m < 8; m <<= 1) {
            mn = fminf(mn, __shfl_xor(mn, m));
            mx = fmaxf(mx, __shfl_xor(mx, m));
        }
        if (l8 == 0) {
            float denom = mx - mn;
            if (denom == 0.f) denom = 1.f;
            ch_mn[c] = mn; ch_inv[c] = 1.f / denom;
        }
    }
    __syncthreads();

    // phase 5: stream h, accumulate squared diff for masked channels
    float acc = 0.f;
    const float* hb = h + (size_t)b * CHE;
    for (int i = tid; i < CHE; i += 256) {
        int c = i / PIX;
        if (!ch_mask[c]) continue;         // diff masked to 0; skip h read too
        float tt = (filt[i] - ch_mn[c]) * ch_inv[c];
        float d  = hb[i] - tt;
        acc += d * d;
    }
    #pragma unroll
    for (int off = 32; off > 0; off >>= 1) acc += __shfl_down(acc, off);
    if ((tid & 63) == 0) wred[tid >> 6] = acc;
    __syncthreads();
    if (tid == 0) {
        partials[b] = wred[0] + wred[1] + wred[2] + wred[3];
        vsums[b]    = (float)svsum;
    }
}

__global__ __launch_bounds__(256) void finalize_kernel(
    const float* __restrict__ partials, const float* __restrict__ vsums,
    float* __restrict__ out)
{
    __shared__ float w1[4], w2[4];
    int tid = threadIdx.x;
    float s = 0.f, vs = 0.f;
    for (int i = tid; i < NB; i += 256) { s += partials[i]; vs += vsums[i]; }
    #pragma unroll
    for (int off = 32; off > 0; off >>= 1) {
        s  += __shfl_down(s, off);
        vs += __shfl_down(vs, off);
    }
    if ((tid & 63) == 0) { w1[tid >> 6] = s; w2[tid >> 6] = vs; }
    __syncthreads();
    if (tid == 0) {
        float stot = w1[0] + w1[1] + w1[2] + w1[3];
        float vtot = w2[0] + w2[1] + w2[2] + w2[3];
        out[0] = stot / (vtot * 0.5f);
    }
}

extern "C" void kernel_launch(void* const* d_in, const int* in_sizes, int n_in,
                              void* d_out, int out_size, void* d_ws, size_t ws_size,
                              hipStream_t stream) {
    // inputs: 0=os (UNUSED), 1=h [B,18,14,14] f32, 2=t [B,14,2] f32, 3=v [B,14,2] i32
    const float* h = (const float*)d_in[1];
    const float* t = (const float*)d_in[2];
    const int*   v = (const int*)d_in[3];
    float* ws       = (float*)d_ws;
    float* partials = ws;            // NB floats
    float* vsums    = ws + NB;       // NB floats

    mse_partial_kernel<<<NB, 256, 0, stream>>>(h, t, v, partials, vsums);
    finalize_kernel<<<1, 256, 0, stream>>>(partials, vsums, (float*)d_out);
}

// Round 2
// 37.334 us; speedup vs baseline: 1.8641x; 1.8641x over previous
//
#include <hip/hip_runtime.h>

#define NB   8192
#define NJ   14
#define NC   18
#define PIX  196           // 14*14
#define CHE  (NC * PIX)    // 3528 floats per batch
#define BPB  4             // batches per block
#define NBLK (NB / BPB)    // 2048 blocks
#define CH4  (CHE / 4)     // 882 float4 chunks per batch
#define NCH4 (BPB * CH4)   // 3528 chunks per block

// unnormalized gaussian taps exp(-0.5*k^2), k=-4..4 ; sum = 2.5066208042307818
#define WSUM_INV 0.398943491f /* 1/2.5066208042307818 */

__global__ __launch_bounds__(256) void mse_partial_kernel(
    const float* __restrict__ h, const float* __restrict__ t,
    const int* __restrict__ v, float* __restrict__ partials,
    float* __restrict__ vsums)
{
    __shared__ float g[14][14];
    __shared__ float gmn[14], gmx[14];
    __shared__ float st[BPB * 28];
    __shared__ int   sv[BPB * 28];
    __shared__ float smn[BPB * NC], sinv[BPB * NC];
    __shared__ int   spos[BPB * NC];   // np | y0<<4 | x0<<8 | y1<<12 | x1<<16 | y2<<20 | x2<<24
    __shared__ float wvs[BPB];
    __shared__ float wred[BPB];

    const int tid = threadIdx.x;
    const int b0  = blockIdx.x * BPB;

    // ---- phase 0: load t/v for 4 batches; build g table (independent) ----
    if (tid < BPB * 28)            st[tid] = t[b0 * 28 + tid];
    else if (tid < 2 * BPB * 28)   sv[tid - BPB * 28] = v[b0 * 28 + (tid - BPB * 28)];
    if (tid < PIX) {
        const float wl[9] = {0.00033546262f, 0.011108997f, 0.13533528f, 0.60653066f,
                             1.0f, 0.60653066f, 0.13533528f, 0.011108997f, 0.00033546262f};
        int p = tid / 14, r = tid - 14 * p;
        float acc = 0.f;
        #pragma unroll
        for (int k = 0; k < 9; k++) {
            int m  = r + k - 4;
            int sm = m < 0 ? (-m - 1) : (m > 13 ? 27 - m : m);  // symmetric reflect
            if (sm == p) acc += wl[k];
        }
        g[p][r] = acc * WSUM_INV;
    }
    __syncthreads();

    // ---- phase 0c: per-row min/max of g (g >= 0) ----
    if (tid < 14) {
        float mn = 1e30f, mx = -1e30f;
        #pragma unroll
        for (int r = 0; r < 14; r++) { float x = g[tid][r]; mn = fminf(mn, x); mx = fmaxf(mx, x); }
        gmn[tid] = mn; gmx[tid] = mx;
    }
    __syncthreads();

    // ---- phase 1: per-wave (= per-batch) channel metadata ----
    const int w = tid >> 6, lane = tid & 63;
    int xi = 0, yi = 0, vis = 0;
    if (lane < NJ) {
        float fx = st[w * 28 + 2 * lane];       // t[...,0] -> x (col)
        float fy = st[w * 28 + 2 * lane + 1];   // t[...,1] -> y (row)
        xi = (int)(fx * 14.0f); xi = xi < 0 ? 0 : (xi > 13 ? 13 : xi);
        yi = (int)(fy * 14.0f); yi = yi < 0 ? 0 : (yi > 13 ? 13 : yi);
        vis = (sv[w * 28 + 2 * lane] == 1);
        if (vis) {
            float mn = gmn[yi] * gmn[xi], mx = gmx[yi] * gmx[xi];  // separable: g >= 0
            float den = mx - mn; if (den == 0.f) den = 1.f;
            smn[w * NC + lane]  = mn;
            sinv[w * NC + lane] = 1.f / den;
            spos[w * NC + lane] = 1 | (yi << 4) | (xi << 8);
        } else {
            spos[w * NC + lane] = 0;
        }
    }
    // batch v-sum via ballot (v in {0,1})
    {
        int vval = (lane < 28) ? sv[w * 28 + lane] : 0;
        unsigned long long bal = __ballot(vval == 1);
        if (lane == 0) wvs[w] = (float)__popcll(bal);
    }
    // group channels: dedup positions, then O(1) or wave-parallel min/max
    for (int gi = 0; gi < 4; gi++) {
        int j0 = 3 * gi;
        int y0 = __shfl(yi, j0),     x0 = __shfl(xi, j0),     v0 = __shfl(vis, j0);
        int y1 = __shfl(yi, j0 + 1), x1 = __shfl(xi, j0 + 1), v1 = __shfl(vis, j0 + 1);
        int y2 = __shfl(yi, j0 + 2), x2 = __shfl(xi, j0 + 2), v2 = __shfl(vis, j0 + 2);
        int py[3], px[3], np = 0;
        if (v0) { py[0] = y0; px[0] = x0; np = 1; }
        if (v1) {
            bool dup = (np > 0 && py[0] == y1 && px[0] == x1);
            if (!dup) { py[np] = y1; px[np] = x1; np++; }
        }
        if (v2) {
            bool dup = false;
            for (int q = 0; q < np; q++) if (py[q] == y2 && px[q] == x2) dup = true;
            if (!dup) { py[np] = y2; px[np] = x2; np++; }
        }
        int c = NJ + gi;
        if (np == 0) {
            if (lane == 0) spos[w * NC + c] = 0;
        } else if (np == 1) {
            if (lane == 0) {
                float mn = gmn[py[0]] * gmn[px[0]], mx = gmx[py[0]] * gmx[px[0]];
                float den = mx - mn; if (den == 0.f) den = 1.f;
                smn[w * NC + c]  = mn;
                sinv[w * NC + c] = 1.f / den;
                spos[w * NC + c] = 1 | (py[0] << 4) | (px[0] << 8);
            }
        } else {
            float mn = 1e30f, mx = -1e30f;
            for (int e = lane; e < PIX; e += 64) {
                int rr = e / 14, cc = e - 14 * rr;
                float f = 0.f;
                for (int q = 0; q < np; q++) f += g[py[q]][rr] * g[px[q]][cc];
                mn = fminf(mn, f); mx = fmaxf(mx, f);
            }
            #pragma unroll
            for (int m = 1; m < 64; m <<= 1) {
                mn = fminf(mn, __shfl_xor(mn, m));
                mx = fmaxf(mx, __shfl_xor(mx, m));
            }
            if (lane == 0) {
                float den = mx - mn; if (den == 0.f) den = 1.f;
                smn[w * NC + c]  = mn;
                sinv[w * NC + c] = 1.f / den;
                int pp = np;
                for (int q = 0; q < np; q++) pp |= (py[q] << (4 + 8 * q)) | (px[q] << (8 + 8 * q));
                spos[w * NC + c] = pp;
            }
        }
    }
    __syncthreads();

    // ---- phase 2: stream h as float4, tt on the fly, skip masked channels ----
    float acc = 0.f;
    const float4* hb4 = (const float4*)(h + (size_t)b0 * CHE);
    for (int k = tid; k < NCH4; k += 256) {
        int wb  = k / CH4;            // batch within block
        int rem = k - wb * CH4;
        int c   = rem / 49;           // channel (49 float4 per channel)
        int p4  = rem - c * 49;
        int pp  = spos[wb * NC + c];
        int np  = pp & 15;
        if (np == 0) continue;        // masked channel: no load, no math
        float mn  = smn[wb * NC + c];
        float inv = sinv[wb * NC + c];
        float4 hv = hb4[k];
        int pix0 = p4 * 4;
        int rr = pix0 / 14;
        int cc = pix0 - 14 * rr;
        float hx[4] = {hv.x, hv.y, hv.z, hv.w};
        #pragma unroll
        for (int j = 0; j < 4; j++) {
            float f = 0.f;
            #pragma unroll
            for (int q = 0; q < 3; q++) {
                if (q < np) {
                    int yq = (pp >> (4 + 8 * q)) & 15;
                    int xq = (pp >> (8 + 8 * q)) & 15;
                    f += g[yq][rr] * g[xq][cc];
                }
            }
            float tt = (f - mn) * inv;
            float d  = hx[j] - tt;
            acc += d * d;
            cc++; if (cc == 14) { cc = 0; rr++; }
        }
    }

    // ---- reduce ----
    #pragma unroll
    for (int off = 32; off > 0; off >>= 1) acc += __shfl_down(acc, off);
    if (lane == 0) wred[w] = acc;
    __syncthreads();
    if (tid == 0) {
        partials[blockIdx.x] = wred[0] + wred[1] + wred[2] + wred[3];
        vsums[blockIdx.x]    = wvs[0] + wvs[1] + wvs[2] + wvs[3];
    }
}

__global__ __launch_bounds__(256) void finalize_kernel(
    const float* __restrict__ partials, const float* __restrict__ vsums,
    float* __restrict__ out)
{
    __shared__ float w1[4], w2[4];
    int tid = threadIdx.x;
    float s = 0.f, vs = 0.f;
    for (int i = tid; i < NBLK; i += 256) { s += partials[i]; vs += vsums[i]; }
    #pragma unroll
    for (int off = 32; off > 0; off >>= 1) {
        s  += __shfl_down(s, off);
        vs += __shfl_down(vs, off);
    }
    if ((tid & 63) == 0) { w1[tid >> 6] = s; w2[tid >> 6] = vs; }
    __syncthreads();
    if (tid == 0) {
        float stot = w1[0] + w1[1] + w1[2] + w1[3];
        float vtot = w2[0] + w2[1] + w2[2] + w2[3];
        out[0] = stot / (vtot * 0.5f);
    }
}

extern "C" void kernel_launch(void* const* d_in, const int* in_sizes, int n_in,
                              void* d_out, int out_size, void* d_ws, size_t ws_size,
                              hipStream_t stream) {
    // inputs: 0=os (UNUSED), 1=h [B,18,14,14] f32, 2=t [B,14,2] f32, 3=v [B,14,2] i32
    const float* h = (const float*)d_in[1];
    const float* t = (const float*)d_in[2];
    const int*   v = (const int*)d_in[3];
    float* ws       = (float*)d_ws;
    float* partials = ws;             // NBLK floats
    float* vsums    = ws + NBLK;      // NBLK floats

    mse_partial_kernel<<<NBLK, 256, 0, stream>>>(h, t, v, partials, vsums);
    finalize_kernel<<<1, 256, 0, stream>>>(partials, vsums, (float*)d_out);
}

// Round 3
// 30.847 us; speedup vs baseline: 2.2561x; 1.2103x over previous
//
#include <hip/hip_runtime.h>

#define NB   8192
#define NJ   14
#define NC   18
#define PIX  196            // 14*14
#define CHE  (NC * PIX)     // 3528 floats per batch
#define CHE4 (CHE / 4)      // 882 float4 per batch
#define BPB  4              // batches per block
#define NBLK (NB / BPB)     // 2048 blocks

#define WSUM_INV 0.398943491f   // 1 / sum(exp(-k^2/2), k=-4..4)

__global__ __launch_bounds__(256) void mse_partial_kernel(
    const float* __restrict__ h, const float* __restrict__ t,
    const int* __restrict__ v, float2* __restrict__ partials)
{
    __shared__ float  gs[15 * 14];     // g[p][r] blurred-delta table; row 14 = zeros
    __shared__ float  gmn[14], gmx[14];
    __shared__ float  st[BPB * 28];
    __shared__ int    sv[BPB * 28];
    __shared__ int    cnt[BPB];
    __shared__ float4 list[BPB * NC];  // {mn, inv, pos_bits, base4_bits} per ACTIVE channel
    __shared__ float  wvs[BPB];
    __shared__ float  wred[BPB];

    const int tid = threadIdx.x;
    const int b0  = blockIdx.x * BPB;
    const int w   = tid >> 6, lane = tid & 63;

    // ---- phase 0: raw t/v loads + g table (rows 0..13 blur, row 14 zero) ----
    if (tid < BPB * 28)               st[tid] = t[b0 * 28 + tid];
    else if (tid < 2 * BPB * 28)      sv[tid - BPB * 28] = v[b0 * 28 + (tid - BPB * 28)];
    if (tid < 210) {
        float val = 0.f;
        if (tid < PIX) {
            const float wl[9] = {0.00033546262f, 0.011108997f, 0.13533528f, 0.60653066f,
                                 1.0f, 0.60653066f, 0.13533528f, 0.011108997f, 0.00033546262f};
            int p = tid / 14, r = tid - 14 * p;
            float acc = 0.f;
            #pragma unroll
            for (int k = 0; k < 9; k++) {
                int m  = r + k - 4;
                int sm = m < 0 ? (-m - 1) : (m > 13 ? 27 - m : m);  // symmetric reflect
                if (sm == p) acc += wl[k];
            }
            val = acc * WSUM_INV;
        }
        gs[tid] = val;
    }
    __syncthreads();

    if (tid < 14) {
        float mn = 1e30f, mx = -1e30f;
        #pragma unroll
        for (int r = 0; r < 14; r++) { float x = gs[tid * 14 + r]; mn = fminf(mn, x); mx = fmaxf(mx, x); }
        gmn[tid] = mn; gmx[tid] = mx;
    }
    __syncthreads();

    // ---- phase 1: per-wave (= per-batch) channel metadata ----
    int xi = 0, yi = 0, vis = 0;
    if (lane < NJ) {
        float fx = st[w * 28 + 2 * lane];       // t[...,0] -> x (col)
        float fy = st[w * 28 + 2 * lane + 1];   // t[...,1] -> y (row)
        xi = (int)(fx * 14.0f); xi = xi < 0 ? 0 : (xi > 13 ? 13 : xi);
        yi = (int)(fy * 14.0f); yi = yi < 0 ? 0 : (yi > 13 ? 13 : yi);
        vis = (sv[w * 28 + 2 * lane] == 1);
    }
    // per-lane channel meta (channel index = lane, valid for lane < NC)
    float mn_c = 0.f, inv_c = 0.f;
    int   pos_c = 0, act_c = 0;
    if (lane < NJ && vis) {
        float mn = gmn[yi] * gmn[xi], mx = gmx[yi] * gmx[xi];   // separable, g >= 0
        float den = mx - mn; if (den == 0.f) den = 1.f;
        mn_c = mn; inv_c = 1.f / den; act_c = 1;
        pos_c = yi | (xi << 4) | (14 << 8) | (14 << 16);        // slots 1,2 -> zero row
    }
    // group channels: all lanes compute redundantly (shfl broadcast); lane 14+gi keeps
    for (int gi = 0; gi < 4; gi++) {
        int j0 = 3 * gi;
        int ys[3], xs[3], vs_[3];
        #pragma unroll
        for (int q = 0; q < 3; q++) {
            ys[q]  = __shfl(yi,  j0 + q);
            xs[q]  = __shfl(xi,  j0 + q);
            vs_[q] = __shfl(vis, j0 + q);
        }
        int packed = 0, np = 0;
        #pragma unroll
        for (int q = 0; q < 3; q++) {
            if (vs_[q]) {
                bool dup = false;
                for (int s = 0; s < np; s++) {
                    int yq = (packed >> (8 * s)) & 15, xq = (packed >> (8 * s + 4)) & 15;
                    if (yq == ys[q] && xq == xs[q]) dup = true;
                }
                if (!dup) { packed |= (ys[q] << (8 * np)) | (xs[q] << (8 * np + 4)); np++; }
            }
        }
        float mn = 0.f, mx = 0.f;
        if (np == 1) {
            int y0p = packed & 15, x0p = (packed >> 4) & 15;
            mn = gmn[y0p] * gmn[x0p]; mx = gmx[y0p] * gmx[x0p];
        } else if (np >= 2) {       // wave-uniform condition: full-wave eval of 196 pixels
            float lmn = 1e30f, lmx = -1e30f;
            for (int e = lane; e < PIX; e += 64) {
                int rr = e / 14, cc = e - 14 * rr;
                float f = 0.f;
                for (int q = 0; q < np; q++) {
                    int yq = (packed >> (8 * q)) & 15, xq = (packed >> (8 * q + 4)) & 15;
                    f += gs[yq * 14 + rr] * gs[xq * 14 + cc];
                }
                lmn = fminf(lmn, f); lmx = fmaxf(lmx, f);
            }
            #pragma unroll
            for (int m = 1; m < 64; m <<= 1) {
                lmn = fminf(lmn, __shfl_xor(lmn, m));
                lmx = fmaxf(lmx, __shfl_xor(lmx, m));
            }
            mn = lmn; mx = lmx;
        }
        if (lane == NJ + gi && np > 0) {
            float den = mx - mn; if (den == 0.f) den = 1.f;
            mn_c = mn; inv_c = 1.f / den; act_c = 1;
            int pos = 0;
            #pragma unroll
            for (int q = 0; q < 3; q++) {
                int yq = q < np ? (packed >> (8 * q)) & 15 : 14;
                int xq = q < np ? (packed >> (8 * q + 4)) & 15 : 0;
                pos |= (yq << (8 * q)) | (xq << (8 * q + 4));
            }
            pos_c = pos;
        }
    }
    // batch v-sum via ballot (v in {0,1}, both components)
    {
        int vval = (lane < 28) ? sv[w * 28 + lane] : 0;
        unsigned long long bal = __ballot(vval == 1);
        if (lane == 0) wvs[w] = (float)__popcll(bal);
    }
    // ballot-compact active channels into per-wave counts
    unsigned long long abal = __ballot(act_c != 0);
    if (lane == 0) cnt[w] = __popcll(abal);
    int lidx = __popcll(abal & ((1ull << lane) - 1ull));
    __syncthreads();

    int off_w = 0;
    #pragma unroll
    for (int q = 0; q < BPB; q++) if (q < w) off_w += cnt[q];
    const int nact = cnt[0] + cnt[1] + cnt[2] + cnt[3];

    if (act_c) {
        float4 e;
        e.x = mn_c; e.y = inv_c;
        e.z = __int_as_float(pos_c);
        e.w = __int_as_float(w * CHE4 + lane * 49);
        list[off_w + lidx] = e;
    }
    __syncthreads();

    // ---- phase 2: branchless stream of ACTIVE chunks, unrolled x2 ----
    const float4* hb4 = (const float4*)(h + (size_t)b0 * CHE);
    const int ntot4 = nact * 49;
    float acc = 0.f;

    auto proc4 = [&](float4 mv, int wi, float4 hv) -> float {
        int   p   = __float_as_int(mv.z);
        float mn  = mv.x, inv = mv.y;
        int y0p =  p        & 15, x0p = (p >> 4)  & 15;
        int y1p = (p >> 8)  & 15, x1p = (p >> 12) & 15;
        int y2p = (p >> 16) & 15, x2p = (p >> 20) & 15;
        int pix0 = wi * 4;
        int rr = pix0 / 14, cc = pix0 - 14 * rr;
        float hx[4] = {hv.x, hv.y, hv.z, hv.w};
        float s = 0.f;
        #pragma unroll
        for (int j = 0; j < 4; j++) {
            float f = gs[y0p * 14 + rr] * gs[x0p * 14 + cc]
                    + gs[y1p * 14 + rr] * gs[x1p * 14 + cc]
                    + gs[y2p * 14 + rr] * gs[x2p * 14 + cc];
            float d = hx[j] - (f - mn) * inv;
            s += d * d;
            cc++; if (cc == 14) { cc = 0; rr++; }
        }
        return s;
    };

    for (int k0 = tid; k0 < ntot4; k0 += 512) {
        int  k1   = k0 + 256;
        bool has1 = k1 < ntot4;
        int  ke   = has1 ? k1 : k0;

        int e0 = k0 / 49, wi0 = k0 - 49 * e0;
        int e1 = ke / 49, wi1 = ke - 49 * e1;
        float4 m0 = list[e0];
        float4 m1 = list[e1];
        int base0 = __float_as_int(m0.w) + wi0;
        int base1 = __float_as_int(m1.w) + wi1;
        float4 hv0 = hb4[base0];          // both loads unconditional & independent
        float4 hv1 = hb4[base1];

        acc += proc4(m0, wi0, hv0);
        float s1 = proc4(m1, wi1, hv1);
        acc += has1 ? s1 : 0.f;
    }

    // ---- reduce ----
    #pragma unroll
    for (int off = 32; off > 0; off >>= 1) acc += __shfl_down(acc, off);
    if (lane == 0) wred[w] = acc;
    __syncthreads();
    if (tid == 0) {
        float2 p;
        p.x = wred[0] + wred[1] + wred[2] + wred[3];
        p.y = wvs[0] + wvs[1] + wvs[2] + wvs[3];
        partials[blockIdx.x] = p;
    }
}

__global__ __launch_bounds__(1024) void finalize_kernel(
    const float2* __restrict__ partials, float* __restrict__ out)
{
    __shared__ float w1[16], w2[16];
    int tid = threadIdx.x;
    float s = 0.f, vs = 0.f;
    #pragma unroll
    for (int i = 0; i < NBLK / 1024; i++) {
        float2 p = partials[tid + i * 1024];
        s += p.x; vs += p.y;
    }
    #pragma unroll
    for (int off = 32; off > 0; off >>= 1) {
        s  += __shfl_down(s, off);
        vs += __shfl_down(vs, off);
    }
    if ((tid & 63) == 0) { w1[tid >> 6] = s; w2[tid >> 6] = vs; }
    __syncthreads();
    if (tid == 0) {
        float stot = 0.f, vtot = 0.f;
        #pragma unroll
        for (int q = 0; q < 16; q++) { stot += w1[q]; vtot += w2[q]; }
        out[0] = stot / (vtot * 0.5f);
    }
}

extern "C" void kernel_launch(void* const* d_in, const int* in_sizes, int n_in,
                              void* d_out, int out_size, void* d_ws, size_t ws_size,
                              hipStream_t stream) {
    // inputs: 0=os (UNUSED), 1=h [B,18,14,14] f32, 2=t [B,14,2] f32, 3=v [B,14,2] i32
    const float* h = (const float*)d_in[1];
    const float* t = (const float*)d_in[2];
    const int*   v = (const int*)d_in[3];
    float2* partials = (float2*)d_ws;   // NBLK float2

    mse_partial_kernel<<<NBLK, 256, 0, stream>>>(h, t, v, partials);
    finalize_kernel<<<1, 1024, 0, stream>>>(partials, (float*)d_out);
}